// Round 1
// baseline (1510.954 us; speedup 1.0000x reference)
//
#include <hip/hip_runtime.h>
#include <math.h>

// Problem: B=8, N=2048, D=512, K=16
// Pipeline:
//  k_norm   : fp32 xn = x/|x| (candidate GEMM input) + fp64 1/|x| (exact rescore)
//  per batch:
//   k_gemm  : sims = xn_b @ xn_b^T (fp32, approximate — used only for candidates)
//   k_topk  : per row: top-32 by approx sims -> exact fp64 rescore -> bitonic
//             sort (val desc, idx asc) -> write top-16 indices (rank order!)
//  k_attn   : logits x@attn_w^T+b, mutual-knn check, 16-wide softmax -> p
//  k_merge  : merged = sum_k p_k * x[neighbor_k]
//  k_gemm   : out  = relu(merged @ w_merged^T)   (op=1)
//  k_gemm   : out += x @ w_orig^T                (op=2)

#define NTOK 2048
#define DIM 512

__global__ __launch_bounds__(64) void k_norm(const float* __restrict__ x,
                                             float* __restrict__ xn,
                                             double* __restrict__ inv64) {
  int row = blockIdx.x, lane = threadIdx.x;
  const float* xr = x + (size_t)row * DIM;
  float4 a = *(const float4*)&xr[lane * 8];
  float4 b = *(const float4*)&xr[lane * 8 + 4];
  double ss = (double)a.x * a.x + (double)a.y * a.y + (double)a.z * a.z +
              (double)a.w * a.w + (double)b.x * b.x + (double)b.y * b.y +
              (double)b.z * b.z + (double)b.w * b.w;
#pragma unroll
  for (int off = 32; off >= 1; off >>= 1) ss += __shfl_xor(ss, off);
  double inv = 1.0 / sqrt(ss);
  if (lane == 0) inv64[row] = inv;
  float f = (float)inv;
  float4 o0 = {a.x * f, a.y * f, a.z * f, a.w * f};
  float4 o1 = {b.x * f, b.y * f, b.z * f, b.w * f};
  *(float4*)&xn[(size_t)row * DIM + lane * 8] = o0;
  *(float4*)&xn[(size_t)row * DIM + lane * 8 + 4] = o1;
}

// C[m*ldc+n] = op( sum_e A[m*512+e]*B[n*512+e] ) ; tiles 128x128, BK=16, 8x8/thread
// op: 0 = write, 1 = relu+write, 2 = add to existing C
__global__ __launch_bounds__(256) void k_gemm(const float* __restrict__ A,
                                              const float* __restrict__ B,
                                              float* __restrict__ C, int ldc,
                                              int op) {
  __shared__ float As[16 * 128];
  __shared__ float Bs[16 * 128];
  int tid = threadIdx.x;
  int tx = tid & 15, ty = tid >> 4;
  int rb = blockIdx.x * 128, cb = blockIdx.y * 128;
  float acc[8][8] = {};
  for (int kt = 0; kt < DIM; kt += 16) {
#pragma unroll
    for (int q = tid; q < 512; q += 256) {
      int r = q >> 2, seg = (q & 3) << 2;
      const float4 va = *(const float4*)&A[(size_t)(rb + r) * DIM + kt + seg];
      As[(seg + 0) * 128 + r] = va.x;
      As[(seg + 1) * 128 + r] = va.y;
      As[(seg + 2) * 128 + r] = va.z;
      As[(seg + 3) * 128 + r] = va.w;
      const float4 vb = *(const float4*)&B[(size_t)(cb + r) * DIM + kt + seg];
      Bs[(seg + 0) * 128 + r] = vb.x;
      Bs[(seg + 1) * 128 + r] = vb.y;
      Bs[(seg + 2) * 128 + r] = vb.z;
      Bs[(seg + 3) * 128 + r] = vb.w;
    }
    __syncthreads();
#pragma unroll
    for (int k = 0; k < 16; ++k) {
      float a[8], bv[8];
      *(float4*)&a[0] = *(const float4*)&As[k * 128 + ty * 8];
      *(float4*)&a[4] = *(const float4*)&As[k * 128 + ty * 8 + 4];
      *(float4*)&bv[0] = *(const float4*)&Bs[k * 128 + tx * 8];
      *(float4*)&bv[4] = *(const float4*)&Bs[k * 128 + tx * 8 + 4];
#pragma unroll
      for (int i = 0; i < 8; ++i)
#pragma unroll
        for (int j = 0; j < 8; ++j) acc[i][j] = fmaf(a[i], bv[j], acc[i][j]);
    }
    __syncthreads();
  }
#pragma unroll
  for (int i = 0; i < 8; ++i) {
    float* cp = C + (size_t)(rb + ty * 8 + i) * ldc + cb + tx * 8;
    float v[8];
#pragma unroll
    for (int j = 0; j < 8; ++j) v[j] = acc[i][j];
    if (op == 1) {
#pragma unroll
      for (int j = 0; j < 8; ++j) v[j] = fmaxf(v[j], 0.0f);
    } else if (op == 2) {
      float4 o0 = *(const float4*)cp;
      float4 o1 = *(const float4*)(cp + 4);
      v[0] += o0.x; v[1] += o0.y; v[2] += o0.z; v[3] += o0.w;
      v[4] += o1.x; v[5] += o1.y; v[6] += o1.z; v[7] += o1.w;
    }
    *(float4*)cp = make_float4(v[0], v[1], v[2], v[3]);
    *(float4*)(cp + 4) = make_float4(v[4], v[5], v[6], v[7]);
  }
}

__device__ inline unsigned long long packkey(float v, int idx) {
  unsigned u = __float_as_uint(v);
  u = (u & 0x80000000u) ? ~u : (u | 0x80000000u);
  return ((unsigned long long)u << 32) | (unsigned)(~(unsigned)idx);
}

// one wave per row: extract top-32 by approx sims, fp64-rescore, bitonic sort,
// emit top-16 indices in exact rank order.
__global__ __launch_bounds__(64) void k_topk(const float* __restrict__ sims,
                                             const float* __restrict__ x,
                                             const double* __restrict__ inv64,
                                             int* __restrict__ idx16,
                                             int batch) {
  int n = blockIdx.x;
  int lane = threadIdx.x;
  const float* srow = sims + (size_t)n * NTOK;
  float v[32];
#pragma unroll
  for (int j = 0; j < 32; ++j) v[j] = srow[lane + 64 * j];

  unsigned long long thresh = ~0ULL;
  unsigned long long bkey = 0;
  bool dirty = true;
  int mycand = 0;
  for (int r = 0; r < 32; ++r) {
    if (dirty) {
      bkey = 0;
#pragma unroll
      for (int j = 0; j < 32; ++j) {
        unsigned long long key = packkey(v[j], lane + 64 * j);
        if (key < thresh && key > bkey) bkey = key;
      }
      dirty = false;
    }
    unsigned long long w = bkey;
#pragma unroll
    for (int off = 1; off < 64; off <<= 1) {
      unsigned long long o = __shfl_xor(w, off);
      if (o > w) w = o;
    }
    if (w == bkey) {  // unique winner (keys embed unique index)
      thresh = bkey;
      dirty = true;
    }
    if (r == (lane & 31)) mycand = (int)(~(unsigned)(w & 0xFFFFFFFFu));
  }

  // exact fp64 rescore: lane pairs (c, c+32) split the 512-dim dot
  int c = lane & 31, h = lane >> 5;
  int m = mycand;  // lane and lane^32 hold the same candidate index
  const float* xa = x + ((size_t)batch * NTOK + n) * DIM + h * 256;
  const float* xb = x + ((size_t)batch * NTOK + m) * DIM + h * 256;
  double s = 0.0;
#pragma unroll 4
  for (int t = 0; t < 256; t += 4) {
    float4 a = *(const float4*)&xa[t];
    float4 b = *(const float4*)&xb[t];
    s = fma((double)a.x, (double)b.x, s);
    s = fma((double)a.y, (double)b.y, s);
    s = fma((double)a.z, (double)b.z, s);
    s = fma((double)a.w, (double)b.w, s);
  }
  s += __shfl_xor(s, 32);
  double val = s * inv64[batch * NTOK + n] * inv64[batch * NTOK + m];

  // bitonic sort lanes 0..31 by (val desc, idx asc)
  double sv = (lane < 32) ? val : -1.0e300;
  int si = (lane < 32) ? m : 0x7FFFFFFF;
#pragma unroll
  for (int k = 2; k <= 32; k <<= 1) {
#pragma unroll
    for (int j = k >> 1; j > 0; j >>= 1) {
      double ov = __shfl_xor(sv, j);
      int oi = __shfl_xor(si, j);
      bool lower = (lane & j) == 0;
      bool desc = (lane & k) == 0;
      bool takeFirst = (lower == desc);
      bool otherFirst = (ov > sv) || (ov == sv && oi < si);
      if (takeFirst == otherFirst) { sv = ov; si = oi; }
    }
  }
  if (lane < 16) idx16[((size_t)batch * NTOK + n) * 16 + lane] = si;
  (void)c;
}

// one wave per row: logits, mutual check, 16-wide softmax -> p[row][16]
__global__ __launch_bounds__(64) void k_attn(const float* __restrict__ x,
                                             const float* __restrict__ aw,
                                             const float* __restrict__ ab,
                                             const int* __restrict__ idx16,
                                             float* __restrict__ p) {
  int row = blockIdx.x;
  int b = row >> 11, n = row & (NTOK - 1);
  int lane = threadIdx.x;
  int k = lane & 15, q = lane >> 4;
  const float* xr = x + (size_t)row * DIM + q * 128;
  const float* wr = aw + (size_t)k * DIM + q * 128;
  float s = 0.0f;
#pragma unroll 8
  for (int t = 0; t < 128; t += 4) {
    float4 a = *(const float4*)&xr[t];
    float4 w4 = *(const float4*)&wr[t];
    s = fmaf(a.x, w4.x, s);
    s = fmaf(a.y, w4.y, s);
    s = fmaf(a.z, w4.z, s);
    s = fmaf(a.w, w4.w, s);
  }
  s += __shfl_xor(s, 16);
  s += __shfl_xor(s, 32);
  float logit = s + ab[k];

  int m = idx16[(size_t)row * 16 + k];
  const int* mrow = idx16 + ((size_t)(b * NTOK + m)) * 16;
  bool mut = false;
#pragma unroll
  for (int j = 0; j < 16; ++j) mut |= (mrow[j] == n);

  float l = mut ? logit : -__builtin_inff();
  float mx = l;
#pragma unroll
  for (int off = 1; off < 16; off <<= 1) mx = fmaxf(mx, __shfl_xor(mx, off));
  float e = mut ? __expf(l - mx) : 0.0f;
  float den = e;
#pragma unroll
  for (int off = 1; off < 16; off <<= 1) den += __shfl_xor(den, off);
  if (lane < 16) p[(size_t)row * 16 + lane] = e / den;
}

__global__ __launch_bounds__(128) void k_merge(const float* __restrict__ x,
                                               const int* __restrict__ idx16,
                                               const float* __restrict__ p,
                                               float* __restrict__ merged) {
  int row = blockIdx.x;
  int b = row >> 11;
  int t = threadIdx.x;
  __shared__ float ps[16];
  __shared__ int ms[16];
  if (t < 16) {
    ps[t] = p[(size_t)row * 16 + t];
    ms[t] = idx16[(size_t)row * 16 + t];
  }
  __syncthreads();
  float4 acc = {0.f, 0.f, 0.f, 0.f};
#pragma unroll
  for (int k = 0; k < 16; ++k) {
    float pk = ps[k];
    if (pk != 0.0f) {  // uniform across block
      const float4 v = *(const float4*)&x[((size_t)(b * NTOK + ms[k])) * DIM + t * 4];
      acc.x = fmaf(pk, v.x, acc.x);
      acc.y = fmaf(pk, v.y, acc.y);
      acc.z = fmaf(pk, v.z, acc.z);
      acc.w = fmaf(pk, v.w, acc.w);
    }
  }
  *(float4*)&merged[(size_t)row * DIM + t * 4] = acc;
}

extern "C" void kernel_launch(void* const* d_in, const int* in_sizes, int n_in,
                              void* d_out, int out_size, void* d_ws,
                              size_t ws_size, hipStream_t stream) {
  const float* x = (const float*)d_in[0];
  const float* attn_w = (const float*)d_in[1];
  const float* attn_b = (const float*)d_in[2];
  const float* w_merged = (const float*)d_in[3];
  const float* w_orig = (const float*)d_in[4];
  float* out = (float*)d_out;

  char* w = (char*)d_ws;
  float* xn = (float*)w;                          // 33,554,432 B
  double* inv64 = (double*)(w + 33554432);        //    131,072 B
  float* sims = (float*)(w + 33685504);           // 16,777,216 B (per-batch)
  int* idx16 = (int*)(w + 50462720);              //  1,048,576 B
  float* p = (float*)(w + 51511296);              //  1,048,576 B
  float* merged = xn;  // alias: xn dead after last k_topk, merged written after

  k_norm<<<16384, 64, 0, stream>>>(x, xn, inv64);
  for (int b = 0; b < 8; ++b) {
    const float* xnb = xn + (size_t)b * NTOK * DIM;
    k_gemm<<<dim3(16, 16), 256, 0, stream>>>(xnb, xnb, sims, NTOK, 0);
    k_topk<<<NTOK, 64, 0, stream>>>(sims, x, inv64, idx16, b);
  }
  k_attn<<<16384, 64, 0, stream>>>(x, attn_w, attn_b, idx16, p);
  k_merge<<<16384, 128, 0, stream>>>(x, idx16, p, merged);
  k_gemm<<<dim3(128, 4), 256, 0, stream>>>(merged, w_merged, out, DIM, 1);
  k_gemm<<<dim3(128, 4), 256, 0, stream>>>(x, w_orig, out, DIM, 2);
}

// Round 2
// 580.038 us; speedup vs baseline: 2.6049x; 2.6049x over previous
//
#include <hip/hip_runtime.h>
#include <math.h>

// Problem: B=8, N=2048, D=512, K=16
// R2: all GEMMs -> bf16 MFMA (16x16x32), m97-style 128x128 tile with
// global_load_lds width=16. Candidate selection on bf16 sims, exact fp64
// rescore + bitonic rank -> reference-exact top-16 ordering.

#define NTOK 2048
#define DIM 512

typedef __attribute__((ext_vector_type(8))) __bf16 bf16x8;
typedef __attribute__((ext_vector_type(4))) float f32x4;

#define GLDS(gp, lp)                                                      \
  __builtin_amdgcn_global_load_lds(                                       \
      (const __attribute__((address_space(1))) void*)(gp),                \
      (__attribute__((address_space(3))) void*)(lp), 16, 0, 0)

__device__ __forceinline__ ushort f2b(float f) {  // RNE fp32->bf16
  unsigned u = __float_as_uint(f);
  return (ushort)((u + 0x7fffu + ((u >> 16) & 1u)) >> 16);
}

// ---------------- norm: xnb = bf16(x/|x|), xb = bf16(x), inv64 = 1/|x| ------
__global__ __launch_bounds__(64) void k_norm(const float* __restrict__ x,
                                             ushort* __restrict__ xnb,
                                             ushort* __restrict__ xb,
                                             double* __restrict__ inv64) {
  int row = blockIdx.x, lane = threadIdx.x;
  const float* xr = x + (size_t)row * DIM;
  float4 a = *(const float4*)&xr[lane * 8];
  float4 b = *(const float4*)&xr[lane * 8 + 4];
  double ss = (double)a.x * a.x + (double)a.y * a.y + (double)a.z * a.z +
              (double)a.w * a.w + (double)b.x * b.x + (double)b.y * b.y +
              (double)b.z * b.z + (double)b.w * b.w;
#pragma unroll
  for (int off = 32; off >= 1; off >>= 1) ss += __shfl_xor(ss, off);
  double inv = 1.0 / sqrt(ss);
  if (lane == 0) inv64[row] = inv;
  float f = (float)inv;
  size_t o = (size_t)row * DIM + lane * 8;
  ushort4 r0 = {f2b(a.x), f2b(a.y), f2b(a.z), f2b(a.w)};
  ushort4 r1 = {f2b(b.x), f2b(b.y), f2b(b.z), f2b(b.w)};
  *(ushort4*)&xb[o] = r0;
  *(ushort4*)&xb[o + 4] = r1;
  ushort4 n0 = {f2b(a.x * f), f2b(a.y * f), f2b(a.z * f), f2b(a.w * f)};
  ushort4 n1 = {f2b(b.x * f), f2b(b.y * f), f2b(b.z * f), f2b(b.w * f)};
  *(ushort4*)&xnb[o] = n0;
  *(ushort4*)&xnb[o + 4] = n1;
}

__global__ __launch_bounds__(256) void k_castw(const float* __restrict__ a,
                                               const float* __restrict__ b,
                                               ushort* __restrict__ ab,
                                               ushort* __restrict__ bb) {
  int i = (blockIdx.x * 256 + threadIdx.x) * 4;  // 256 blocks -> 262144 elems
  float4 va = *(const float4*)&a[i];
  float4 vb = *(const float4*)&b[i];
  ushort4 oa = {f2b(va.x), f2b(va.y), f2b(va.z), f2b(va.w)};
  ushort4 ob = {f2b(vb.x), f2b(vb.y), f2b(vb.z), f2b(vb.w)};
  *(ushort4*)&ab[i] = oa;
  *(ushort4*)&bb[i] = ob;
}

// ------------- shared bf16 MFMA K-loop: C128x128 += A(rb..)[.,k]*B(cb..)[.,k]
__device__ __forceinline__ void bt_kloop(const ushort* __restrict__ A,
                                         const ushort* __restrict__ B,
                                         ushort* lA, ushort* lB, int rb, int cb,
                                         int tid, f32x4 (&acc)[4][4]) {
  int wv = tid >> 6, ln = tid & 63;
  int wm = wv >> 1, wn = wv & 1;
  int col = ln & 15, quad = ln >> 4;
  for (int kt = 0; kt < DIM; kt += 32) {
#pragma unroll
    for (int j = 0; j < 2; ++j) {
      int c = j * 256 + wv * 64 + ln;
      int r = c >> 2, seg = c & 3;
      GLDS(A + (size_t)(rb + r) * DIM + kt + seg * 8, lA + c * 8);
      GLDS(B + (size_t)(cb + r) * DIM + kt + seg * 8, lB + c * 8);
    }
    __syncthreads();
    bf16x8 af[4], bf[4];
#pragma unroll
    for (int i = 0; i < 4; ++i) {
      af[i] = *(const bf16x8*)&lA[(wm * 64 + i * 16 + col) * 32 + quad * 8];
      bf[i] = *(const bf16x8*)&lB[(wn * 64 + i * 16 + col) * 32 + quad * 8];
    }
#pragma unroll
    for (int i = 0; i < 4; ++i)
#pragma unroll
      for (int j = 0; j < 4; ++j)
        acc[i][j] =
            __builtin_amdgcn_mfma_f32_16x16x32_bf16(af[i], bf[j], acc[i][j], 0, 0, 0);
    __syncthreads();
  }
}

// sims (fp32) = Xn_b @ Xn_b^T for pb batches (blockIdx.z)
__global__ __launch_bounds__(256) void k_simgemm(const ushort* __restrict__ Xn,
                                                 float* __restrict__ S) {
  __shared__ ushort lA[128 * 32];
  __shared__ ushort lB[128 * 32];
  int tid = threadIdx.x;
  int z = blockIdx.z;
  const ushort* Xb = Xn + (size_t)z * NTOK * DIM;
  float* Sb = S + (size_t)z * NTOK * NTOK;
  int rb = blockIdx.x * 128, cb = blockIdx.y * 128;
  f32x4 zero = {0.f, 0.f, 0.f, 0.f};
  f32x4 acc[4][4];
#pragma unroll
  for (int i = 0; i < 4; ++i)
#pragma unroll
    for (int j = 0; j < 4; ++j) acc[i][j] = zero;
  bt_kloop(Xb, Xb, lA, lB, rb, cb, tid, acc);
  int wv = tid >> 6, ln = tid & 63;
  int wm = wv >> 1, wn = wv & 1;
  int col = ln & 15, quad = ln >> 4;
#pragma unroll
  for (int i = 0; i < 4; ++i)
#pragma unroll
    for (int j = 0; j < 4; ++j)
#pragma unroll
      for (int r = 0; r < 4; ++r) {
        int m = rb + wm * 64 + i * 16 + quad * 4 + r;
        int n = cb + wn * 64 + j * 16 + col;
        Sb[(size_t)m * NTOK + n] = acc[i][j][r];
      }
}

// out = relu(Mg@Wm^T) + Xg@Wo^T, all bf16 inputs, fp32 out
__global__ __launch_bounds__(256) void k_proj(const ushort* __restrict__ Mg,
                                              const ushort* __restrict__ Wm,
                                              const ushort* __restrict__ Xg,
                                              const ushort* __restrict__ Wo,
                                              float* __restrict__ out) {
  __shared__ ushort lA[128 * 32];
  __shared__ ushort lB[128 * 32];
  int tid = threadIdx.x;
  int rb = blockIdx.x * 128, cb = blockIdx.y * 128;
  f32x4 zero = {0.f, 0.f, 0.f, 0.f};
  f32x4 a1[4][4], a2[4][4];
#pragma unroll
  for (int i = 0; i < 4; ++i)
#pragma unroll
    for (int j = 0; j < 4; ++j) { a1[i][j] = zero; a2[i][j] = zero; }
  bt_kloop(Mg, Wm, lA, lB, rb, cb, tid, a1);
  bt_kloop(Xg, Wo, lA, lB, rb, cb, tid, a2);
  int wv = tid >> 6, ln = tid & 63;
  int wm = wv >> 1, wn = wv & 1;
  int col = ln & 15, quad = ln >> 4;
#pragma unroll
  for (int i = 0; i < 4; ++i)
#pragma unroll
    for (int j = 0; j < 4; ++j)
#pragma unroll
      for (int r = 0; r < 4; ++r) {
        int m = rb + wm * 64 + i * 16 + quad * 4 + r;
        int n = cb + wn * 64 + j * 16 + col;
        out[(size_t)m * DIM + n] = fmaxf(a1[i][j][r], 0.f) + a2[i][j][r];
      }
}

__device__ inline unsigned long long packkey(float v, int idx) {
  unsigned u = __float_as_uint(v);
  u = (u & 0x80000000u) ? ~u : (u | 0x80000000u);
  return ((unsigned long long)u << 32) | (unsigned)(~(unsigned)idx);
}

// one wave per row: top-32 by approx sims -> fp64 rescore -> bitonic ->
// top-16 indices in exact rank order.
__global__ __launch_bounds__(64) void k_topk(const float* __restrict__ sims,
                                             const float* __restrict__ x,
                                             const double* __restrict__ inv64,
                                             int* __restrict__ idx16,
                                             int batch0) {
  int n = blockIdx.x;
  int batch = batch0 + blockIdx.y;
  int lane = threadIdx.x;
  const float* srow = sims + (size_t)blockIdx.y * NTOK * NTOK + (size_t)n * NTOK;
  float v[32];
#pragma unroll
  for (int j = 0; j < 32; ++j) v[j] = srow[lane + 64 * j];

  unsigned long long thresh = ~0ULL;
  unsigned long long bkey = 0;
  bool dirty = true;
  int mycand = 0;
  for (int r = 0; r < 32; ++r) {
    if (dirty) {
      bkey = 0;
#pragma unroll
      for (int j = 0; j < 32; ++j) {
        unsigned long long key = packkey(v[j], lane + 64 * j);
        if (key < thresh && key > bkey) bkey = key;
      }
      dirty = false;
    }
    unsigned long long w = bkey;
#pragma unroll
    for (int off = 1; off < 64; off <<= 1) {
      unsigned long long o = __shfl_xor(w, off);
      if (o > w) w = o;
    }
    if (w == bkey) { thresh = bkey; dirty = true; }
    if (r == (lane & 31)) mycand = (int)(~(unsigned)(w & 0xFFFFFFFFu));
  }

  int h = lane >> 5;
  int m = mycand;
  const float* xa = x + ((size_t)batch * NTOK + n) * DIM + h * 256;
  const float* xb = x + ((size_t)batch * NTOK + m) * DIM + h * 256;
  double s = 0.0;
#pragma unroll 4
  for (int t = 0; t < 256; t += 4) {
    float4 a = *(const float4*)&xa[t];
    float4 b = *(const float4*)&xb[t];
    s = fma((double)a.x, (double)b.x, s);
    s = fma((double)a.y, (double)b.y, s);
    s = fma((double)a.z, (double)b.z, s);
    s = fma((double)a.w, (double)b.w, s);
  }
  s += __shfl_xor(s, 32);
  double val = s * inv64[batch * NTOK + n] * inv64[batch * NTOK + m];

  double sv = (lane < 32) ? val : -1.0e300;
  int si = (lane < 32) ? m : 0x7FFFFFFF;
#pragma unroll
  for (int k = 2; k <= 32; k <<= 1) {
#pragma unroll
    for (int j = k >> 1; j > 0; j >>= 1) {
      double ov = __shfl_xor(sv, j);
      int oi = __shfl_xor(si, j);
      bool lower = (lane & j) == 0;
      bool desc = (lane & k) == 0;
      bool takeFirst = (lower == desc);
      bool otherFirst = (ov > sv) || (ov == sv && oi < si);
      if (takeFirst == otherFirst) { sv = ov; si = oi; }
    }
  }
  if (lane < 16) idx16[((size_t)batch * NTOK + n) * 16 + lane] = si;
}

// one wave per row: logits, mutual check, 16-wide softmax -> p[row][16]
__global__ __launch_bounds__(64) void k_attn(const float* __restrict__ x,
                                             const float* __restrict__ aw,
                                             const float* __restrict__ ab,
                                             const int* __restrict__ idx16,
                                             float* __restrict__ p) {
  int row = blockIdx.x;
  int b = row >> 11, n = row & (NTOK - 1);
  int lane = threadIdx.x;
  int k = lane & 15, q = lane >> 4;
  const float* xr = x + (size_t)row * DIM + q * 128;
  const float* wr = aw + (size_t)k * DIM + q * 128;
  float s = 0.0f;
#pragma unroll 8
  for (int t = 0; t < 128; t += 4) {
    float4 a = *(const float4*)&xr[t];
    float4 w4 = *(const float4*)&wr[t];
    s = fmaf(a.x, w4.x, s);
    s = fmaf(a.y, w4.y, s);
    s = fmaf(a.z, w4.z, s);
    s = fmaf(a.w, w4.w, s);
  }
  s += __shfl_xor(s, 16);
  s += __shfl_xor(s, 32);
  float logit = s + ab[k];

  int m = idx16[(size_t)row * 16 + k];
  const int* mrow = idx16 + ((size_t)(b * NTOK + m)) * 16;
  bool mut = false;
#pragma unroll
  for (int j = 0; j < 16; ++j) mut |= (mrow[j] == n);

  float l = mut ? logit : -__builtin_inff();
  float mx = l;
#pragma unroll
  for (int off = 1; off < 16; off <<= 1) mx = fmaxf(mx, __shfl_xor(mx, off));
  float e = mut ? __expf(l - mx) : 0.0f;
  float den = e;
#pragma unroll
  for (int off = 1; off < 16; off <<= 1) den += __shfl_xor(den, off);
  if (lane < 16) p[(size_t)row * 16 + lane] = e / den;
}

__global__ __launch_bounds__(128) void k_merge(const float* __restrict__ x,
                                               const int* __restrict__ idx16,
                                               const float* __restrict__ p,
                                               ushort* __restrict__ mergedb) {
  int row = blockIdx.x;
  int b = row >> 11;
  int t = threadIdx.x;
  __shared__ float ps[16];
  __shared__ int ms[16];
  if (t < 16) {
    ps[t] = p[(size_t)row * 16 + t];
    ms[t] = idx16[(size_t)row * 16 + t];
  }
  __syncthreads();
  float4 acc = {0.f, 0.f, 0.f, 0.f};
#pragma unroll
  for (int k = 0; k < 16; ++k) {
    float pk = ps[k];
    if (pk != 0.0f) {
      const float4 v = *(const float4*)&x[((size_t)(b * NTOK + ms[k])) * DIM + t * 4];
      acc.x = fmaf(pk, v.x, acc.x);
      acc.y = fmaf(pk, v.y, acc.y);
      acc.z = fmaf(pk, v.z, acc.z);
      acc.w = fmaf(pk, v.w, acc.w);
    }
  }
  ushort4 o = {f2b(acc.x), f2b(acc.y), f2b(acc.z), f2b(acc.w)};
  *(ushort4*)&mergedb[(size_t)row * DIM + t * 4] = o;
}

extern "C" void kernel_launch(void* const* d_in, const int* in_sizes, int n_in,
                              void* d_out, int out_size, void* d_ws,
                              size_t ws_size, hipStream_t stream) {
  const float* x = (const float*)d_in[0];
  const float* attn_w = (const float*)d_in[1];
  const float* attn_b = (const float*)d_in[2];
  const float* w_merged = (const float*)d_in[3];
  const float* w_orig = (const float*)d_in[4];
  float* out = (float*)d_out;

  char* w = (char*)d_ws;
  ushort* xnb = (ushort*)(w);                 // 16,777,216
  ushort* xb = (ushort*)(w + 16777216);       // 16,777,216
  double* inv64 = (double*)(w + 33554432);    //    131,072
  ushort* wmb = (ushort*)(w + 33685504);      //    524,288
  ushort* wob = (ushort*)(w + 34209792);      //    524,288
  int* idx16 = (int*)(w + 34734080);          //  1,048,576
  float* p = (float*)(w + 35782656);          //  1,048,576
  float* sims = (float*)(w + 36831232);       // 16.7 MB (pb=1) / 33.5 MB (pb=2)
  ushort* mergedb = (ushort*)(w + 36831232);  // alias: sims dead after topk loop

  int pb = (ws_size >= 70385664ull) ? 2 : 1;

  k_norm<<<16384, 64, 0, stream>>>(x, xnb, xb, inv64);
  k_castw<<<256, 256, 0, stream>>>(w_merged, w_orig, wmb, wob);
  for (int b = 0; b < 8; b += pb) {
    k_simgemm<<<dim3(16, 16, pb), 256, 0, stream>>>(xnb + (size_t)b * NTOK * DIM, sims);
    k_topk<<<dim3(NTOK, pb), 64, 0, stream>>>(sims, x, inv64, idx16, b);
  }
  k_attn<<<16384, 64, 0, stream>>>(x, attn_w, attn_b, idx16, p);
  k_merge<<<16384, 128, 0, stream>>>(x, idx16, p, mergedb);
  k_proj<<<dim3(128, 4), 256, 0, stream>>>(mergedb, wmb, xb, wob, out);
}

// Round 3
// 433.907 us; speedup vs baseline: 3.4822x; 1.3368x over previous
//
#include <hip/hip_runtime.h>
#include <math.h>

// Problem: B=8, N=2048, D=512, K=16
// R3: fuse attn logits into k_norm; fuse mutual+softmax into k_merge (bf16
// gathers); k_topk selection on 32-bit keys; batch sim GEMMs via blockIdx.z.

#define NTOK 2048
#define DIM 512

typedef __attribute__((ext_vector_type(8))) __bf16 bf16x8;
typedef __attribute__((ext_vector_type(4))) float f32x4;

#define GLDS(gp, lp)                                                      \
  __builtin_amdgcn_global_load_lds(                                       \
      (const __attribute__((address_space(1))) void*)(gp),                \
      (__attribute__((address_space(3))) void*)(lp), 16, 0, 0)

__device__ __forceinline__ ushort f2b(float f) {  // RNE fp32->bf16
  unsigned u = __float_as_uint(f);
  return (ushort)((u + 0x7fffu + ((u >> 16) & 1u)) >> 16);
}
__device__ __forceinline__ float b2f(ushort h) {
  return __uint_as_float((unsigned)h << 16);
}

// norm: xnb=bf16(x/|x|), xb=bf16(x), inv64=1/|x|, L=x@aw^T+ab (fp32 logits)
__global__ __launch_bounds__(64) void k_norm(const float* __restrict__ x,
                                             const float* __restrict__ aw,
                                             const float* __restrict__ ab,
                                             ushort* __restrict__ xnb,
                                             ushort* __restrict__ xb,
                                             double* __restrict__ inv64,
                                             float* __restrict__ L) {
  int row = blockIdx.x, lane = threadIdx.x;
  const float* xr = x + (size_t)row * DIM;
  float4 a = *(const float4*)&xr[lane * 8];
  float4 b = *(const float4*)&xr[lane * 8 + 4];

  // 16 attn logits: independent accumulation chains, then butterfly reduce
  float s[16];
#pragma unroll
  for (int k = 0; k < 16; ++k) {
    const float4 w0 = *(const float4*)&aw[(size_t)k * DIM + lane * 8];
    const float4 w1 = *(const float4*)&aw[(size_t)k * DIM + lane * 8 + 4];
    s[k] = a.x * w0.x + a.y * w0.y + a.z * w0.z + a.w * w0.w + b.x * w1.x +
           b.y * w1.y + b.z * w1.z + b.w * w1.w;
  }
#pragma unroll
  for (int off = 1; off < 64; off <<= 1)
#pragma unroll
    for (int k = 0; k < 16; ++k) s[k] += __shfl_xor(s[k], off);

  double ss = (double)a.x * a.x + (double)a.y * a.y + (double)a.z * a.z +
              (double)a.w * a.w + (double)b.x * b.x + (double)b.y * b.y +
              (double)b.z * b.z + (double)b.w * b.w;
#pragma unroll
  for (int off = 32; off >= 1; off >>= 1) ss += __shfl_xor(ss, off);
  double inv = 1.0 / sqrt(ss);
  if (lane == 0) {
    inv64[row] = inv;
#pragma unroll
    for (int k = 0; k < 16; ++k) L[(size_t)row * 16 + k] = s[k] + ab[k];
  }
  float f = (float)inv;
  size_t o = (size_t)row * DIM + lane * 8;
  ushort4 r0 = {f2b(a.x), f2b(a.y), f2b(a.z), f2b(a.w)};
  ushort4 r1 = {f2b(b.x), f2b(b.y), f2b(b.z), f2b(b.w)};
  *(ushort4*)&xb[o] = r0;
  *(ushort4*)&xb[o + 4] = r1;
  ushort4 n0 = {f2b(a.x * f), f2b(a.y * f), f2b(a.z * f), f2b(a.w * f)};
  ushort4 n1 = {f2b(b.x * f), f2b(b.y * f), f2b(b.z * f), f2b(b.w * f)};
  *(ushort4*)&xnb[o] = n0;
  *(ushort4*)&xnb[o + 4] = n1;
}

__global__ __launch_bounds__(256) void k_castw(const float* __restrict__ a,
                                               const float* __restrict__ b,
                                               ushort* __restrict__ ab,
                                               ushort* __restrict__ bb) {
  int i = (blockIdx.x * 256 + threadIdx.x) * 4;
  float4 va = *(const float4*)&a[i];
  float4 vb = *(const float4*)&b[i];
  ushort4 oa = {f2b(va.x), f2b(va.y), f2b(va.z), f2b(va.w)};
  ushort4 ob = {f2b(vb.x), f2b(vb.y), f2b(vb.z), f2b(vb.w)};
  *(ushort4*)&ab[i] = oa;
  *(ushort4*)&bb[i] = ob;
}

// shared bf16 MFMA K-loop (B^T): C128x128 += A[rb..][k]*B[cb..][k]
__device__ __forceinline__ void bt_kloop(const ushort* __restrict__ A,
                                         const ushort* __restrict__ B,
                                         ushort* lA, ushort* lB, int rb, int cb,
                                         int tid, f32x4 (&acc)[4][4]) {
  int wv = tid >> 6, ln = tid & 63;
  int wm = wv >> 1, wn = wv & 1;
  int col = ln & 15, quad = ln >> 4;
  for (int kt = 0; kt < DIM; kt += 32) {
#pragma unroll
    for (int j = 0; j < 2; ++j) {
      int c = j * 256 + wv * 64 + ln;
      int r = c >> 2, seg = c & 3;
      GLDS(A + (size_t)(rb + r) * DIM + kt + seg * 8, lA + c * 8);
      GLDS(B + (size_t)(cb + r) * DIM + kt + seg * 8, lB + c * 8);
    }
    __syncthreads();
    bf16x8 af[4], bf[4];
#pragma unroll
    for (int i = 0; i < 4; ++i) {
      af[i] = *(const bf16x8*)&lA[(wm * 64 + i * 16 + col) * 32 + quad * 8];
      bf[i] = *(const bf16x8*)&lB[(wn * 64 + i * 16 + col) * 32 + quad * 8];
    }
#pragma unroll
    for (int i = 0; i < 4; ++i)
#pragma unroll
      for (int j = 0; j < 4; ++j)
        acc[i][j] =
            __builtin_amdgcn_mfma_f32_16x16x32_bf16(af[i], bf[j], acc[i][j], 0, 0, 0);
    __syncthreads();
  }
}

// sims (fp32) = Xn_z @ Xn_z^T, z = blockIdx.z
__global__ __launch_bounds__(256) void k_simgemm(const ushort* __restrict__ Xn,
                                                 float* __restrict__ S) {
  __shared__ ushort lA[128 * 32];
  __shared__ ushort lB[128 * 32];
  int tid = threadIdx.x;
  int z = blockIdx.z;
  const ushort* Xb = Xn + (size_t)z * NTOK * DIM;
  float* Sb = S + (size_t)z * NTOK * NTOK;
  int rb = blockIdx.x * 128, cb = blockIdx.y * 128;
  f32x4 zero = {0.f, 0.f, 0.f, 0.f};
  f32x4 acc[4][4];
#pragma unroll
  for (int i = 0; i < 4; ++i)
#pragma unroll
    for (int j = 0; j < 4; ++j) acc[i][j] = zero;
  bt_kloop(Xb, Xb, lA, lB, rb, cb, tid, acc);
  int wv = tid >> 6, ln = tid & 63;
  int wm = wv >> 1, wn = wv & 1;
  int col = ln & 15, quad = ln >> 4;
#pragma unroll
  for (int i = 0; i < 4; ++i)
#pragma unroll
    for (int j = 0; j < 4; ++j)
#pragma unroll
      for (int r = 0; r < 4; ++r) {
        int m = rb + wm * 64 + i * 16 + quad * 4 + r;
        int n = cb + wn * 64 + j * 16 + col;
        Sb[(size_t)m * NTOK + n] = acc[i][j][r];
      }
}

// out = relu(Mg@Wm^T) + Xg@Wo^T
__global__ __launch_bounds__(256) void k_proj(const ushort* __restrict__ Mg,
                                              const ushort* __restrict__ Wm,
                                              const ushort* __restrict__ Xg,
                                              const ushort* __restrict__ Wo,
                                              float* __restrict__ out) {
  __shared__ ushort lA[128 * 32];
  __shared__ ushort lB[128 * 32];
  int tid = threadIdx.x;
  int rb = blockIdx.x * 128, cb = blockIdx.y * 128;
  f32x4 zero = {0.f, 0.f, 0.f, 0.f};
  f32x4 a1[4][4], a2[4][4];
#pragma unroll
  for (int i = 0; i < 4; ++i)
#pragma unroll
    for (int j = 0; j < 4; ++j) { a1[i][j] = zero; a2[i][j] = zero; }
  bt_kloop(Mg, Wm, lA, lB, rb, cb, tid, a1);
  bt_kloop(Xg, Wo, lA, lB, rb, cb, tid, a2);
  int wv = tid >> 6, ln = tid & 63;
  int wm = wv >> 1, wn = wv & 1;
  int col = ln & 15, quad = ln >> 4;
#pragma unroll
  for (int i = 0; i < 4; ++i)
#pragma unroll
    for (int j = 0; j < 4; ++j)
#pragma unroll
      for (int r = 0; r < 4; ++r) {
        int m = rb + wm * 64 + i * 16 + quad * 4 + r;
        int n = cb + wn * 64 + j * 16 + col;
        out[(size_t)m * DIM + n] = fmaxf(a1[i][j][r], 0.f) + a2[i][j][r];
      }
}

// one wave per row: top-32 by 32-bit packed keys -> fp64 rescore -> bitonic
// -> top-16 indices in exact (reference) rank order.
__global__ __launch_bounds__(64) void k_topk(const float* __restrict__ sims,
                                             const float* __restrict__ x,
                                             const double* __restrict__ inv64,
                                             int* __restrict__ idx16,
                                             int batch0) {
  int n = blockIdx.x;
  int batch = batch0 + blockIdx.y;
  int lane = threadIdx.x;
  const float* srow =
      sims + (size_t)blockIdx.y * NTOK * NTOK + (size_t)n * NTOK;
  // key = mapped-float top 21 bits | 11-bit column index (globally unique)
  unsigned kv[32];
#pragma unroll
  for (int j = 0; j < 32; ++j) {
    unsigned u = __float_as_uint(srow[lane + 64 * j]);
    u = (u & 0x80000000u) ? ~u : (u | 0x80000000u);
    kv[j] = (u & 0xFFFFF800u) | (unsigned)(lane + 64 * j);
  }
  unsigned thresh = 0xFFFFFFFFu;
  unsigned bkey = 0;
  bool dirty = true;
  int mycand = 0;
  for (int r = 0; r < 32; ++r) {
    if (dirty) {
      bkey = 0;
#pragma unroll
      for (int j = 0; j < 32; ++j) {
        unsigned key = kv[j];
        if (key < thresh && key > bkey) bkey = key;
      }
      dirty = false;
    }
    unsigned w = bkey;
#pragma unroll
    for (int off = 1; off < 64; off <<= 1) {
      unsigned o = __shfl_xor(w, off);
      if (o > w) w = o;
    }
    if (w == bkey) { thresh = bkey; dirty = true; }  // unique winner
    if (r == (lane & 31)) mycand = (int)(w & 0x7FFu);
  }

  int h = lane >> 5;
  int m = mycand;  // lanes c and c+32 hold the same candidate
  const float* xa = x + ((size_t)batch * NTOK + n) * DIM + h * 256;
  const float* xc = x + ((size_t)batch * NTOK + m) * DIM + h * 256;
  double s = 0.0;
#pragma unroll 4
  for (int t = 0; t < 256; t += 4) {
    float4 a = *(const float4*)&xa[t];
    float4 b = *(const float4*)&xc[t];
    s = fma((double)a.x, (double)b.x, s);
    s = fma((double)a.y, (double)b.y, s);
    s = fma((double)a.z, (double)b.z, s);
    s = fma((double)a.w, (double)b.w, s);
  }
  s += __shfl_xor(s, 32);
  double val = s * inv64[batch * NTOK + n] * inv64[batch * NTOK + m];

  double sv = (lane < 32) ? val : -1.0e300;
  int si = (lane < 32) ? m : 0x7FFFFFFF;
#pragma unroll
  for (int k = 2; k <= 32; k <<= 1) {
#pragma unroll
    for (int j = k >> 1; j > 0; j >>= 1) {
      double ov = __shfl_xor(sv, j);
      int oi = __shfl_xor(si, j);
      bool lower = (lane & j) == 0;
      bool desc = (lane & k) == 0;
      bool takeFirst = (lower == desc);
      bool otherFirst = (ov > sv) || (ov == sv && oi < si);
      if (takeFirst == otherFirst) { sv = ov; si = oi; }
    }
  }
  if (lane < 16) idx16[((size_t)batch * NTOK + n) * 16 + lane] = si;
}

// one block per row: mutual check + 16-wide softmax (wave 0), then weighted
// aggregation of bf16 neighbor rows -> bf16 merged.
__global__ __launch_bounds__(128) void k_merge(const ushort* __restrict__ xb,
                                               const int* __restrict__ idx16,
                                               const float* __restrict__ L,
                                               ushort* __restrict__ mergedb) {
  int row = blockIdx.x;
  int b = row >> 11, n = row & (NTOK - 1);
  int t = threadIdx.x;
  __shared__ float ps[16];
  __shared__ int ms[16];
  if (t < 64) {
    int k = t & 15;
    int m = idx16[(size_t)row * 16 + k];
    const int* mrow = idx16 + (size_t)(b * NTOK + m) * 16;
    int4 q0 = *(const int4*)&mrow[0];
    int4 q1 = *(const int4*)&mrow[4];
    int4 q2 = *(const int4*)&mrow[8];
    int4 q3 = *(const int4*)&mrow[12];
    bool mut = (q0.x == n) | (q0.y == n) | (q0.z == n) | (q0.w == n) |
               (q1.x == n) | (q1.y == n) | (q1.z == n) | (q1.w == n) |
               (q2.x == n) | (q2.y == n) | (q2.z == n) | (q2.w == n) |
               (q3.x == n) | (q3.y == n) | (q3.z == n) | (q3.w == n);
    float l = mut ? L[(size_t)row * 16 + k] : -__builtin_inff();
    float mx = l;
#pragma unroll
    for (int off = 1; off < 16; off <<= 1) mx = fmaxf(mx, __shfl_xor(mx, off));
    float e = mut ? __expf(l - mx) : 0.0f;
    float den = e;
#pragma unroll
    for (int off = 1; off < 16; off <<= 1) den += __shfl_xor(den, off);
    if (t < 16) { ps[t] = e / den; ms[t] = m; }
  }
  __syncthreads();
  float4 acc = {0.f, 0.f, 0.f, 0.f};
#pragma unroll
  for (int k = 0; k < 16; ++k) {
    float pk = ps[k];
    if (pk != 0.0f) {  // uniform across block
      ushort4 v = *(const ushort4*)&xb[(size_t)(b * NTOK + ms[k]) * DIM + t * 4];
      acc.x = fmaf(pk, b2f(v.x), acc.x);
      acc.y = fmaf(pk, b2f(v.y), acc.y);
      acc.z = fmaf(pk, b2f(v.z), acc.z);
      acc.w = fmaf(pk, b2f(v.w), acc.w);
    }
  }
  ushort4 o = {f2b(acc.x), f2b(acc.y), f2b(acc.z), f2b(acc.w)};
  *(ushort4*)&mergedb[(size_t)row * DIM + t * 4] = o;
}

extern "C" void kernel_launch(void* const* d_in, const int* in_sizes, int n_in,
                              void* d_out, int out_size, void* d_ws,
                              size_t ws_size, hipStream_t stream) {
  const float* x = (const float*)d_in[0];
  const float* attn_w = (const float*)d_in[1];
  const float* attn_b = (const float*)d_in[2];
  const float* w_merged = (const float*)d_in[3];
  const float* w_orig = (const float*)d_in[4];
  float* out = (float*)d_out;

  char* w = (char*)d_ws;
  ushort* xnb = (ushort*)(w);                 // 16,777,216
  ushort* xb = (ushort*)(w + 16777216);       // 16,777,216
  double* inv64 = (double*)(w + 33554432);    //    131,072
  ushort* wmb = (ushort*)(w + 33685504);      //    524,288
  ushort* wob = (ushort*)(w + 34209792);      //    524,288
  int* idx16 = (int*)(w + 34734080);          //  1,048,576
  float* L = (float*)(w + 35782656);          //  1,048,576 (logits)
  float* sims = (float*)(w + 36831232);       //  pb x 16,777,216
  ushort* mergedb = (ushort*)(w + 36831232);  // alias: sims dead after topk

  size_t fixed = 36831232ull, per = 16777216ull;
  int pb = 1;
  if (ws_size >= fixed + 8 * per) pb = 8;
  else if (ws_size >= fixed + 4 * per) pb = 4;
  else if (ws_size >= fixed + 2 * per) pb = 2;

  k_norm<<<16384, 64, 0, stream>>>(x, attn_w, attn_b, xnb, xb, inv64, L);
  k_castw<<<256, 256, 0, stream>>>(w_merged, w_orig, wmb, wob);
  for (int b = 0; b < 8; b += pb) {
    k_simgemm<<<dim3(16, 16, pb), 256, 0, stream>>>(
        xnb + (size_t)b * NTOK * DIM, sims);
    k_topk<<<dim3(NTOK, pb), 64, 0, stream>>>(sims, x, inv64, idx16, b);
  }
  k_merge<<<16384, 128, 0, stream>>>(xb, idx16, L, mergedb);
  k_proj<<<dim3(128, 4), 256, 0, stream>>>(mergedb, wmb, xb, wob, out);
}